// Round 13
// baseline (76.994 us; speedup 1.0000x reference)
//
#include <hip/hip_runtime.h>

#define N 256
#define NN 65536

typedef __attribute__((ext_vector_type(8))) __bf16 bf16x8;
typedef __attribute__((ext_vector_type(4))) __bf16 bf16x4v;
typedef __attribute__((ext_vector_type(4))) float f32x4;

// ---- workspace layout (float offsets); ws is ~256MB (R9 fillBuffer evidence)
#define F_PART   0u          // [4096 blocks][64 bl][32 ml] yadj partials (33.5MB)
#define F_CSPART 8388608u    // [8 mt][256 n][256 k] colsum partials
#define F_WSC    8912896u    // [256]
#define F_CSB    8913152u    // 65536 bf16 (32768 floats)
#define F_SFULL  8945920u    // [65536]
#define F_YADJ   9011456u    // [65536]
#define WS_FLOATS 9076992u

static __device__ __forceinline__ f32x4 mfma16(bf16x8 a, bf16x8 b, f32x4 c) {
  return __builtin_amdgcn_mfma_f32_16x16x32_bf16(a, b, c, 0, 0, 0);
}
static __device__ __forceinline__ bf16x4v pack4(float4 v) {
  bf16x4v r;
  r[0] = (__bf16)v.x; r[1] = (__bf16)v.y; r[2] = (__bf16)v.z; r[3] = (__bf16)v.w;
  return r;
}
static __device__ __forceinline__ bf16x8 pack8(float4 a, float4 b) {
  bf16x8 r;
  r[0] = (__bf16)a.x; r[1] = (__bf16)a.y; r[2] = (__bf16)a.z; r[3] = (__bf16)a.w;
  r[4] = (__bf16)b.x; r[5] = (__bf16)b.y; r[6] = (__bf16)b.z; r[7] = (__bf16)b.w;
  return r;
}

// ============================================================================
// kbig v13 "TLP-flood": grid 4096 = bh(4) x mt(8) x s(32) x tp(4); 256 thr
//   (4 waves x 16 b-rows). Each block: just TWO n-tiles (n = s*8+tp*2+{0,1})
//   -> minimal intra-block serialization; ~7 blocks/CU co-resident provide
//   the latency hiding every intra-block pipeline variant (R2-R12) failed
//   to get. Per tile: {8 loads -> stage(16KB) + reg-colsum} sync
//   {16 ds_read + 16 MFMA + yadj fmacs + CS store}. yadj partial (8KB)
//   written to a PRIVATE F_PART slot; kred does the 128-deep reduction.
// LDS: tile 16KB @0 | csl 4KB @16384  (20480 B; wsc red 8KB reuses tile)
// ============================================================================
__global__ void __launch_bounds__(256) kbig(
    const float* __restrict__ X, const float* __restrict__ ctx,
    const float* __restrict__ W, const float* __restrict__ clb,
    const float* __restrict__ clw, float* __restrict__ ws)
{
  extern __shared__ char smem[];
  float* csl = (float*)(smem + 16384);
  float* red = (float*)smem;
  const int t = threadIdx.x;
  const int blk = blockIdx.x;
  const int tp = blk & 3;
  const int s  = (blk >> 2) & 31;
  const int mt = (blk >> 7) & 7;
  const int bh = blk >> 10;
  const int n0 = s * 8 + tp * 2, m0g = mt * 32, b0g = bh * 64;

  const int lane = t & 63, w = t >> 6;
  const int wb = w * 16;
  const int l15 = lane & 15, lhi = lane >> 4;
  const int swz = (l15 & 7) << 4;
  const float4* clwf4 = (const float4*)clw;

  // prologue: ctx -> af (32 VGPRs), X values for the 2 n's -> regs
  bf16x8 af[8];
#pragma unroll
  for (int c = 0; c < 8; ++c) {
    const float4* p = (const float4*)(ctx + (b0g + wb + l15) * N +
                                      c * 32 + lhi * 8);
    af[c] = pack8(p[0], p[1]);
  }
  float xrv[2][4];
#pragma unroll
  for (int TT = 0; TT < 2; ++TT)
#pragma unroll
    for (int r = 0; r < 4; ++r)
      xrv[TT][r] = X[(b0g + wb + lhi * 4 + r) * N + n0 + TT];

  const f32x4 zero = {0.f, 0.f, 0.f, 0.f};
  f32x4 acc[2];
  acc[0] = zero; acc[1] = zero;

#define STAGE(TT)                                                           \
  {                                                                         \
    float4 r[8];                                                            \
    _Pragma("unroll")                                                       \
    for (int i = 0; i < 8; ++i) {                                           \
      const int rowl = w * 8 + i;                                           \
      r[i] = clwf4[(size_t)((m0g + rowl) * 256 + n0 + (TT)) * 64 + lane];   \
    }                                                                       \
    _Pragma("unroll")                                                       \
    for (int i = 0; i < 8; ++i) {                                           \
      const int rowl = w * 8 + i;                                           \
      *(bf16x4v*)(smem + rowl * 512 +                                       \
                  ((lane * 8) ^ ((rowl & 7) << 4))) = pack4(r[i]);          \
    }                                                                       \
    if (bh == 0) {                                                          \
      float4 cso = r[0];                                                    \
      _Pragma("unroll")                                                     \
      for (int i = 1; i < 8; ++i) {                                         \
        cso.x += r[i].x; cso.y += r[i].y;                                   \
        cso.z += r[i].z; cso.w += r[i].w;                                   \
      }                                                                     \
      *(float4*)(csl + w * 256 + lane * 4) = cso;                           \
    }                                                                       \
    __syncthreads();                                                        \
  }

#define COMP(TT)                                                            \
  {                                                                         \
    f32x4 h[2];                                                             \
    h[0] = zero; h[1] = zero;                                               \
    _Pragma("unroll")                                                       \
    for (int c = 0; c < 8; ++c) {                                           \
      const int kb = c * 64 + lhi * 16;                                     \
      bf16x8 b0 = *(const bf16x8*)(smem + l15 * 512 + (kb ^ swz));          \
      bf16x8 b1 = *(const bf16x8*)(smem + (16 + l15) * 512 + (kb ^ swz));   \
      h[0] = mfma16(af[c], b0, h[0]);                                       \
      h[1] = mfma16(af[c], b1, h[1]);                                       \
    }                                                                       \
    _Pragma("unroll")                                                       \
    for (int r = 0; r < 4; ++r) {                                           \
      acc[0][r] += xrv[TT][r] * h[0][r];                                    \
      acc[1][r] += xrv[TT][r] * h[1][r];                                    \
    }                                                                       \
    if (bh == 0) {                                                          \
      float cvv = csl[t] + csl[256 + t] + csl[512 + t] + csl[768 + t];      \
      ws[F_CSPART + mt * 65536u + (size_t)(n0 + (TT)) * 256 + t] = cvv;     \
    }                                                                       \
  }

  STAGE(0)
  COMP(0)
  __syncthreads();
  STAGE(1)
  COMP(1)
#undef STAGE
#undef COMP

  // yadj partial: private slot per block, [64 bl][32 ml] (coalesced, 8KB)
  const size_t base = (size_t)blk * 2048;
#pragma unroll
  for (int fm = 0; fm < 2; ++fm)
#pragma unroll
    for (int r = 0; r < 4; ++r)
      ws[F_PART + base + (wb + lhi * 4 + r) * 32 + fm * 16 + l15] =
          acc[fm][r];

  // wsc: colsum of W+CB for 8 j-columns, by (mt==0,bh==0,tp==0) blocks
  if (mt == 0 && bh == 0 && tp == 0) {
    __syncthreads();
    const float4* wp = (const float4*)(W + t * N + s * 8);
    const float4* cp = (const float4*)(clb + t * N + s * 8);
    const float4 a0 = wp[0], a1 = wp[1], c0 = cp[0], c1 = cp[1];
    red[0 * 256 + t] = a0.x + c0.x; red[1 * 256 + t] = a0.y + c0.y;
    red[2 * 256 + t] = a0.z + c0.z; red[3 * 256 + t] = a0.w + c0.w;
    red[4 * 256 + t] = a1.x + c1.x; red[5 * 256 + t] = a1.y + c1.y;
    red[6 * 256 + t] = a1.z + c1.z; red[7 * 256 + t] = a1.w + c1.w;
    __syncthreads();
    if (t < 64) {
      const int jj = t >> 3, seg = t & 7;
      float v = 0.f;
#pragma unroll
      for (int i = 0; i < 32; ++i) v += red[jj * 256 + seg * 32 + i];
      v += __shfl_xor(v, 1);
      v += __shfl_xor(v, 2);
      v += __shfl_xor(v, 4);
      if (seg == 0) ws[F_WSC + s * 8 + jj] = v;
    }
  }
}

// ============================================================================
// kred: yadj[b,m] = sum over 128 (s,tp) slots; CS = sum_mt CSPART -> bf16
// ============================================================================
__global__ void __launch_bounds__(256) kred(float* __restrict__ ws)
{
  const int o = blockIdx.x * 256 + threadIdx.x;
  const int b = o >> 8, col = o & 255;
  const int mtm = col >> 5, ml = col & 31;
  const int bhh = b >> 6, bl = b & 63;
  const size_t sbase = F_PART + (size_t)(bhh * 1024 + mtm * 128) * 2048 +
                       bl * 32 + ml;
  float y = 0.f;
#pragma unroll 16
  for (int q = 0; q < 128; ++q)
    y += ws[sbase + (size_t)q * 2048];
  ws[F_YADJ + o] = y;
  float cv = 0.f;
#pragma unroll
  for (int q = 0; q < 8; ++q)
    cv += ws[F_CSPART + q * 65536u + o];
  ((__bf16*)(ws + F_CSB))[o] = (__bf16)cv;
}

// ============================================================================
// kred2: SF[b,j] = wsc[j] + sum_k ctx[b,k]*CS[j,k]  (64 blocks, LDS-free)
// ============================================================================
__global__ void __launch_bounds__(256) kred2(
    const float* __restrict__ ctx, float* __restrict__ ws)
{
  const int t = threadIdx.x, blk = blockIdx.x;
  const int b0 = (blk >> 3) * 32, j0 = (blk & 7) * 32;
  const int lane = t & 63, w = t >> 6;
  const int l15 = lane & 15, lhi = lane >> 4;
  const int wqb = (w >> 1) * 16, wqj = (w & 1) * 16;
  const char* csb = (const char*)(ws + F_CSB);

  f32x4 accq = {0.f, 0.f, 0.f, 0.f};
#pragma unroll
  for (int c = 0; c < 8; ++c) {
    const float4* p = (const float4*)(ctx + (b0 + wqb + l15) * N +
                                      c * 32 + lhi * 8);
    bf16x8 a = pack8(p[0], p[1]);
    bf16x8 b = *(const bf16x8*)(csb + (j0 + wqj + l15) * 512 +
                                c * 64 + lhi * 16);
    accq = mfma16(a, b, accq);
  }
  const int j = j0 + wqj + l15;
  const float wscv = ws[F_WSC + j];
#pragma unroll
  for (int r = 0; r < 4; ++r) {
    const int b = b0 + wqb + lhi * 4 + r;
    ws[F_SFULL + b * N + j] = accq[r] + wscv;
  }
}

// ============================================================================
// kfin: unchanged (64 blocks, 2 fused K=256 MFMA chains + epilogue)
// ============================================================================
__global__ void __launch_bounds__(256) kfin(
    const float* __restrict__ X, const float* __restrict__ ctx,
    const float* __restrict__ W, const float* __restrict__ clb,
    const float* __restrict__ A, const float* __restrict__ scale,
    const int* __restrict__ tptr, float* __restrict__ out,
    float* __restrict__ ws)
{
  extern __shared__ char smem[];
  const int t = threadIdx.x, blk = blockIdx.x;
  const int b0 = (blk >> 3) * 32, k0 = (blk & 7) * 32;
  {
    const int row = t >> 3, q = t & 7;
    const int sw = (row & 7) << 4;
    const float4* sp = (const float4*)(ws + F_SFULL + (b0 + row) * N);
    const float4* xp = (const float4*)(X + (b0 + row) * N);
    const float4* wp = (const float4*)(W + (k0 + row) * N);
    const float4* cp = (const float4*)(clb + (k0 + row) * N);
#pragma unroll
    for (int i = 0; i < 8; ++i) {
      const int f4 = q * 8 + i;
      const int off = row * 512 + ((f4 * 8) ^ sw);
      *(bf16x4v*)(smem + off) = pack4(sp[f4]);
      *(bf16x4v*)(smem + 16384 + off) = pack4(xp[f4]);
      const float4 wv = wp[f4], cv = cp[f4];
      float4 s2;
      s2.x = wv.x + cv.x; s2.y = wv.y + cv.y;
      s2.z = wv.z + cv.z; s2.w = wv.w + cv.w;
      *(bf16x4v*)(smem + 49152 + off) = pack4(s2);
    }
    const float4* ap = (const float4*)(A + t * N + k0);
    char* at = smem + 32768;
#pragma unroll
    for (int i = 0; i < 8; ++i) {
      const float4 v = ap[i];
      const int kk = i * 4;
      *(__bf16*)(at + (kk + 0) * 512 + ((t * 2) ^ (((kk + 0) & 7) << 4))) = (__bf16)v.x;
      *(__bf16*)(at + (kk + 1) * 512 + ((t * 2) ^ (((kk + 1) & 7) << 4))) = (__bf16)v.y;
      *(__bf16*)(at + (kk + 2) * 512 + ((t * 2) ^ (((kk + 2) & 7) << 4))) = (__bf16)v.z;
      *(__bf16*)(at + (kk + 3) * 512 + ((t * 2) ^ (((kk + 3) & 7) << 4))) = (__bf16)v.w;
    }
  }
  __syncthreads();
  const int lane = t & 63, w = t >> 6;
  const int l15 = lane & 15, lhi = lane >> 4;
  const int wqb = (w >> 1) * 16, wqk = (w & 1) * 16;
  const int swz = (l15 & 7) << 4;
  f32x4 accd = {0.f, 0.f, 0.f, 0.f}, accw = {0.f, 0.f, 0.f, 0.f};
#pragma unroll
  for (int c = 0; c < 8; ++c) {
    const int kb = c * 64 + lhi * 16;
    bf16x8 as  = *(const bf16x8*)(smem + (wqb + l15) * 512 + (kb ^ swz));
    bf16x8 aat = *(const bf16x8*)(smem + 32768 + (wqk + l15) * 512 + (kb ^ swz));
    bf16x8 ax  = *(const bf16x8*)(smem + 16384 + (wqb + l15) * 512 + (kb ^ swz));
    bf16x8 awc = *(const bf16x8*)(smem + 49152 + (wqk + l15) * 512 + (kb ^ swz));
    accd = mfma16(as, aat, accd);
    accw = mfma16(ax, awc, accw);
  }
  const float sc = scale[0];
  const float tf = (float)(*tptr);
  const float c1 = tf / (tf + 1.f), c2 = 1.f / (tf + 1.f);
#pragma unroll
  for (int r = 0; r < 4; ++r) {
    const int b = b0 + wqb + lhi * 4 + r, k = k0 + wqk + l15;
    const int idx = b * N + k;
    const float xv = X[idx];
    out[idx] = sc * (xv * accd[r] - accw[r] - ws[F_YADJ + idx]);
    out[NN + idx] = ctx[idx] * c1 + xv * c2;
  }
}

extern "C" void kernel_launch(void* const* d_in, const int* in_sizes, int n_in,
                              void* d_out, int out_size, void* d_ws, size_t ws_size,
                              hipStream_t stream)
{
  (void)in_sizes; (void)n_in; (void)out_size;
  const float* X     = (const float*)d_in[0];
  const float* ctx   = (const float*)d_in[1];
  const float* W     = (const float*)d_in[2];
  const float* scale = (const float*)d_in[3];
  const float* A     = (const float*)d_in[4];
  const float* clw   = (const float*)d_in[5];
  const float* clb   = (const float*)d_in[6];
  const int*   tptr  = (const int*)d_in[7];
  float* out = (float*)d_out;
  float* ws  = (float*)d_ws;

  if (ws_size < (size_t)WS_FLOATS * sizeof(float)) return;

  (void)hipFuncSetAttribute((const void*)kfin,
                            hipFuncAttributeMaxDynamicSharedMemorySize, 65536);

  kbig<<<4096, 256, 20480, stream>>>(X, ctx, W, clb, clw, ws);
  kred<<<256, 256, 0, stream>>>(ws);
  kred2<<<64, 256, 0, stream>>>(ctx, ws);
  kfin<<<64, 256, 65536, stream>>>(X, ctx, W, clb, A, scale, tptr, out, ws);
}

// Round 14
// 56.801 us; speedup vs baseline: 1.3555x; 1.3555x over previous
//
#include <hip/hip_runtime.h>

#define N 256
#define NN 65536

typedef __attribute__((ext_vector_type(8))) __bf16 bf16x8;
typedef __attribute__((ext_vector_type(4))) __bf16 bf16x4v;
typedef __attribute__((ext_vector_type(4))) float f32x4;

// ---- workspace layout (float offsets) ----
#define F_PART   0u          // [512 blocks][256 b][16 ml] yadj partials (8MB)
#define F_CSPART 2097152u    // [16 mg][65536 jk] colsum partials (4MB)
#define F_WSC    3145728u    // [256]
#define F_CSB    3145984u    // 65536 bf16 (32768 floats): CS[j][k]
#define F_SFULL  3178752u    // [65536] f32
#define F_YADJ   3244288u    // [65536] f32
#define WS_FLOATS 3309824u

static __device__ __forceinline__ f32x4 mfma16(bf16x8 a, bf16x8 b, f32x4 c) {
  return __builtin_amdgcn_mfma_f32_16x16x32_bf16(a, b, c, 0, 0, 0);
}
static __device__ __forceinline__ bf16x4v pack4(float4 v) {
  bf16x4v r;
  r[0] = (__bf16)v.x; r[1] = (__bf16)v.y; r[2] = (__bf16)v.z; r[3] = (__bf16)v.w;
  return r;
}
static __device__ __forceinline__ bf16x8 pack8(float4 a, float4 b) {
  bf16x8 r;
  r[0] = (__bf16)a.x; r[1] = (__bf16)a.y; r[2] = (__bf16)a.z; r[3] = (__bf16)a.w;
  r[4] = (__bf16)b.x; r[5] = (__bf16)b.y; r[6] = (__bf16)b.z; r[7] = (__bf16)b.w;
  return r;
}

// ============================================================================
// kbig v14 "linear-slab": grid 512 = mg(16) x s(32); 512 thr (8 waves x 32 b).
//   Block (mg,s) owns m in [16mg,16mg+16), n in [8s,8s+8), ALL k: slab =
//   16 contiguous 8KB runs (vs 1KB-granule scatter of R2-R13 that capped
//   HBM at ~2-3 TB/s). clw is read EXACTLY ONCE chip-wide (FETCH = 64MB).
//   Stage: thread t loads run f4[t] of each of 16 m-rows (perfectly
//   coalesced 8KB bursts), reg-colsum over m -> CSPART (free CS), bf16
//   swizzled LDS store. One barrier. Compute: 8 n-steps x {8 ds_read_b128
//   (B shared by both b-frags) + 16 MFMA + yadj fmacs}.
// LDS: buf 64KB @0 = [16m][8n][256k] bf16, k-swizzled | xl[8][256]f32 @65536
//      (73728 B -> 2 blocks/CU; wsc red reuses buf post-compute)
// ============================================================================
__global__ void __launch_bounds__(512) kbig(
    const float* __restrict__ X, const float* __restrict__ ctx,
    const float* __restrict__ W, const float* __restrict__ clb,
    const float* __restrict__ clw, float* __restrict__ ws)
{
  extern __shared__ char smem[];
  float* xl  = (float*)(smem + 65536);
  float* red = (float*)smem;
  const int t = threadIdx.x;
  const int mg = blockIdx.x >> 5, s = blockIdx.x & 31;
  const int m0 = mg * 16, n0 = s * 8;

  const int lane = t & 63, w = t >> 6;
  const int wb = w * 32;
  const int l15 = lane & 15, lhi = lane >> 4;
  const float4* clwf4 = (const float4*)clw;

  // prologue: ctx -> af (A-frags, 32 b-rows/wave), X -> xl
  bf16x8 af[2][8];
#pragma unroll
  for (int i = 0; i < 2; ++i)
#pragma unroll
    for (int c = 0; c < 8; ++c) {
      const float4* p = (const float4*)(ctx + (wb + i * 16 + l15) * N +
                                        c * 32 + lhi * 8);
      af[i][c] = pack8(p[0], p[1]);
    }
  if (t < 256) {  // xl[nn][b] = X[b, n0+nn]
    const float4* xp = (const float4*)(X + t * N + n0);
    const float4 x0 = xp[0], x1 = xp[1];
    xl[0 * 256 + t] = x0.x; xl[1 * 256 + t] = x0.y;
    xl[2 * 256 + t] = x0.z; xl[3 * 256 + t] = x0.w;
    xl[4 * 256 + t] = x1.x; xl[5 * 256 + t] = x1.y;
    xl[6 * 256 + t] = x1.z; xl[7 * 256 + t] = x1.w;
  }

  // ---- stage the 128KB slab: 16 runs of 8KB, thread t takes f4 #t of each
  // run; reg-colsum over the 16 m while values are live ----
  float4 cso = {0.f, 0.f, 0.f, 0.f};
  {
    float4 val[16];
#pragma unroll
    for (int r = 0; r < 16; ++r)
      val[r] = clwf4[(size_t)(m0 + r) * 16384 + n0 * 64 + t];
#pragma unroll
    for (int r = 0; r < 16; ++r) {
      cso.x += val[r].x; cso.y += val[r].y;
      cso.z += val[r].z; cso.w += val[r].w;
      // thread t covers flat elems t*4..t*4+3 => LDS byte t*8 within row r;
      // XOR bits 4-6 with (r&7) de-conflicts the m-strided B-frag reads
      *(bf16x4v*)(smem + r * 4096 + ((t * 8) ^ ((r & 7) << 4))) = pack4(val[r]);
    }
  }
  __syncthreads();

  const f32x4 zero = {0.f, 0.f, 0.f, 0.f};
  f32x4 acc[2];
  acc[0] = zero; acc[1] = zero;

  // ---- compute: 8 n-steps; B-frag = [16m x 32k] from swizzled buf ----
#pragma unroll
  for (int n = 0; n < 8; ++n) {
    f32x4 h[2];
    h[0] = zero; h[1] = zero;
#pragma unroll
    for (int c = 0; c < 8; ++c) {
      const int kbyte = (c * 64 + lhi * 16) ^ ((l15 & 7) << 4);
      bf16x8 bf = *(const bf16x8*)(smem + l15 * 4096 + n * 512 + kbyte);
      h[0] = mfma16(af[0][c], bf, h[0]);
      h[1] = mfma16(af[1][c], bf, h[1]);
    }
#pragma unroll
    for (int r = 0; r < 4; ++r) {
      h[0][r] *= xl[n * 256 + wb + lhi * 4 + r];
      h[1][r] *= xl[n * 256 + wb + 16 + lhi * 4 + r];
      acc[0][r] += h[0][r];
      acc[1][r] += h[1][r];
    }
  }

  // CS partial: thread's (n,k) position summed over this block's 16 m
  *(float4*)(ws + F_CSPART + mg * 65536u + s * 2048 + t * 4) = cso;

  // yadj partial: [block][256 b][16 ml] (coalesced)
  const size_t base = (size_t)blockIdx.x * 4096;
#pragma unroll
  for (int i = 0; i < 2; ++i)
#pragma unroll
    for (int r = 0; r < 4; ++r)
      ws[F_PART + base + (size_t)(wb + i * 16 + lhi * 4 + r) * 16 + l15] =
          acc[i][r];

  // wsc: colsum of W+CB for 8 j-columns, by mg==0 blocks (red reuses buf)
  if (mg == 0) {
    __syncthreads();
    if (t < 256) {
      const float4* wp = (const float4*)(W + t * N + s * 8);
      const float4* cp = (const float4*)(clb + t * N + s * 8);
      const float4 a0 = wp[0], a1 = wp[1], c0 = cp[0], c1 = cp[1];
      red[0 * 256 + t] = a0.x + c0.x; red[1 * 256 + t] = a0.y + c0.y;
      red[2 * 256 + t] = a0.z + c0.z; red[3 * 256 + t] = a0.w + c0.w;
      red[4 * 256 + t] = a1.x + c1.x; red[5 * 256 + t] = a1.y + c1.y;
      red[6 * 256 + t] = a1.z + c1.z; red[7 * 256 + t] = a1.w + c1.w;
    }
    __syncthreads();
    if (t < 64) {
      const int jj = t >> 3, seg = t & 7;
      float v = 0.f;
#pragma unroll
      for (int i = 0; i < 32; ++i) v += red[jj * 256 + seg * 32 + i];
      v += __shfl_xor(v, 1);
      v += __shfl_xor(v, 2);
      v += __shfl_xor(v, 4);
      if (seg == 0) ws[F_WSC + s * 8 + jj] = v;
    }
  }
}

// ============================================================================
// kred: yadj[b,m] = sum over 32 s-slots of PART[(mg,s)][b][ml];
//       CS[jk] = sum over 16 mg of CSPART -> bf16 CSB
// ============================================================================
__global__ void __launch_bounds__(256) kred(float* __restrict__ ws)
{
  const int o = blockIdx.x * 256 + threadIdx.x;
  const int b = o >> 8, m = o & 255;
  const int mgg = m >> 4, ml = m & 15;
  const size_t pb = F_PART + (size_t)(mgg * 32) * 4096 + (size_t)b * 16 + ml;
  float y = 0.f;
#pragma unroll
  for (int si = 0; si < 32; ++si)
    y += ws[pb + (size_t)si * 4096];
  ws[F_YADJ + o] = y;
  float cv = 0.f;
#pragma unroll
  for (int g = 0; g < 16; ++g)
    cv += ws[F_CSPART + g * 65536u + o];
  ((__bf16*)(ws + F_CSB))[o] = (__bf16)cv;
}

// ============================================================================
// kred2: SF[b,j] = wsc[j] + sum_k ctx[b,k]*CS[j,k]  (64 blocks, LDS-free)
// ============================================================================
__global__ void __launch_bounds__(256) kred2(
    const float* __restrict__ ctx, float* __restrict__ ws)
{
  const int t = threadIdx.x, blk = blockIdx.x;
  const int b0 = (blk >> 3) * 32, j0 = (blk & 7) * 32;
  const int lane = t & 63, w = t >> 6;
  const int l15 = lane & 15, lhi = lane >> 4;
  const int wqb = (w >> 1) * 16, wqj = (w & 1) * 16;
  const char* csb = (const char*)(ws + F_CSB);

  f32x4 accq = {0.f, 0.f, 0.f, 0.f};
#pragma unroll
  for (int c = 0; c < 8; ++c) {
    const float4* p = (const float4*)(ctx + (b0 + wqb + l15) * N +
                                      c * 32 + lhi * 8);
    bf16x8 a = pack8(p[0], p[1]);
    bf16x8 b = *(const bf16x8*)(csb + (j0 + wqj + l15) * 512 +
                                c * 64 + lhi * 16);
    accq = mfma16(a, b, accq);
  }
  const int j = j0 + wqj + l15;
  const float wscv = ws[F_WSC + j];
#pragma unroll
  for (int r = 0; r < 4; ++r) {
    const int b = b0 + wqb + lhi * 4 + r;
    ws[F_SFULL + b * N + j] = accq[r] + wscv;
  }
}

// ============================================================================
// kfin: unchanged (64 blocks, 2 fused K=256 MFMA chains + epilogue)
// ============================================================================
__global__ void __launch_bounds__(256) kfin(
    const float* __restrict__ X, const float* __restrict__ ctx,
    const float* __restrict__ W, const float* __restrict__ clb,
    const float* __restrict__ A, const float* __restrict__ scale,
    const int* __restrict__ tptr, float* __restrict__ out,
    float* __restrict__ ws)
{
  extern __shared__ char smem[];
  const int t = threadIdx.x, blk = blockIdx.x;
  const int b0 = (blk >> 3) * 32, k0 = (blk & 7) * 32;
  {
    const int row = t >> 3, q = t & 7;
    const int sw = (row & 7) << 4;
    const float4* sp = (const float4*)(ws + F_SFULL + (b0 + row) * N);
    const float4* xp = (const float4*)(X + (b0 + row) * N);
    const float4* wp = (const float4*)(W + (k0 + row) * N);
    const float4* cp = (const float4*)(clb + (k0 + row) * N);
#pragma unroll
    for (int i = 0; i < 8; ++i) {
      const int f4 = q * 8 + i;
      const int off = row * 512 + ((f4 * 8) ^ sw);
      *(bf16x4v*)(smem + off) = pack4(sp[f4]);
      *(bf16x4v*)(smem + 16384 + off) = pack4(xp[f4]);
      const float4 wv = wp[f4], cv = cp[f4];
      float4 s2;
      s2.x = wv.x + cv.x; s2.y = wv.y + cv.y;
      s2.z = wv.z + cv.z; s2.w = wv.w + cv.w;
      *(bf16x4v*)(smem + 49152 + off) = pack4(s2);
    }
    const float4* ap = (const float4*)(A + t * N + k0);
    char* at = smem + 32768;
#pragma unroll
    for (int i = 0; i < 8; ++i) {
      const float4 v = ap[i];
      const int kk = i * 4;
      *(__bf16*)(at + (kk + 0) * 512 + ((t * 2) ^ (((kk + 0) & 7) << 4))) = (__bf16)v.x;
      *(__bf16*)(at + (kk + 1) * 512 + ((t * 2) ^ (((kk + 1) & 7) << 4))) = (__bf16)v.y;
      *(__bf16*)(at + (kk + 2) * 512 + ((t * 2) ^ (((kk + 2) & 7) << 4))) = (__bf16)v.z;
      *(__bf16*)(at + (kk + 3) * 512 + ((t * 2) ^ (((kk + 3) & 7) << 4))) = (__bf16)v.w;
    }
  }
  __syncthreads();
  const int lane = t & 63, w = t >> 6;
  const int l15 = lane & 15, lhi = lane >> 4;
  const int wqb = (w >> 1) * 16, wqk = (w & 1) * 16;
  const int swz = (l15 & 7) << 4;
  f32x4 accd = {0.f, 0.f, 0.f, 0.f}, accw = {0.f, 0.f, 0.f, 0.f};
#pragma unroll
  for (int c = 0; c < 8; ++c) {
    const int kb = c * 64 + lhi * 16;
    bf16x8 as  = *(const bf16x8*)(smem + (wqb + l15) * 512 + (kb ^ swz));
    bf16x8 aat = *(const bf16x8*)(smem + 32768 + (wqk + l15) * 512 + (kb ^ swz));
    bf16x8 ax  = *(const bf16x8*)(smem + 16384 + (wqb + l15) * 512 + (kb ^ swz));
    bf16x8 awc = *(const bf16x8*)(smem + 49152 + (wqk + l15) * 512 + (kb ^ swz));
    accd = mfma16(as, aat, accd);
    accw = mfma16(ax, awc, accw);
  }
  const float sc = scale[0];
  const float tf = (float)(*tptr);
  const float c1 = tf / (tf + 1.f), c2 = 1.f / (tf + 1.f);
#pragma unroll
  for (int r = 0; r < 4; ++r) {
    const int b = b0 + wqb + lhi * 4 + r, k = k0 + wqk + l15;
    const int idx = b * N + k;
    const float xv = X[idx];
    out[idx] = sc * (xv * accd[r] - accw[r] - ws[F_YADJ + idx]);
    out[NN + idx] = ctx[idx] * c1 + xv * c2;
  }
}

extern "C" void kernel_launch(void* const* d_in, const int* in_sizes, int n_in,
                              void* d_out, int out_size, void* d_ws, size_t ws_size,
                              hipStream_t stream)
{
  (void)in_sizes; (void)n_in; (void)out_size;
  const float* X     = (const float*)d_in[0];
  const float* ctx   = (const float*)d_in[1];
  const float* W     = (const float*)d_in[2];
  const float* scale = (const float*)d_in[3];
  const float* A     = (const float*)d_in[4];
  const float* clw   = (const float*)d_in[5];
  const float* clb   = (const float*)d_in[6];
  const int*   tptr  = (const int*)d_in[7];
  float* out = (float*)d_out;
  float* ws  = (float*)d_ws;

  if (ws_size < (size_t)WS_FLOATS * sizeof(float)) return;

  (void)hipFuncSetAttribute((const void*)kbig,
                            hipFuncAttributeMaxDynamicSharedMemorySize, 73728);
  (void)hipFuncSetAttribute((const void*)kfin,
                            hipFuncAttributeMaxDynamicSharedMemorySize, 65536);

  kbig<<<512, 512, 73728, stream>>>(X, ctx, W, clb, clw, ws);
  kred<<<256, 256, 0, stream>>>(ws);
  kred2<<<64, 256, 0, stream>>>(ctx, ws);
  kfin<<<64, 256, 65536, stream>>>(X, ctx, W, clb, A, scale, tptr, out, ws);
}